// Round 7
// baseline (1376.063 us; speedup 1.0000x reference)
//
#include <hip/hip_runtime.h>

#define N_NODES   50000
#define N_EDGES   1600000
#define N_GRAPHS  512
#define LAYERS    3
#define D         128
#define EF        16
#define BN_EPS    1e-5f

typedef short bf16x8 __attribute__((ext_vector_type(8)));
typedef float f32x4 __attribute__((ext_vector_type(4)));

__device__ __forceinline__ unsigned short f2bf(float f) {   // RNE f32->bf16
    unsigned u = __builtin_bit_cast(unsigned, f);
    u += 0x7FFF + ((u >> 16) & 1);
    return (unsigned short)(u >> 16);
}

__device__ __forceinline__ float bf2f(unsigned short u) {
    return __builtin_bit_cast(float, (unsigned)u << 16);
}

__device__ __forceinline__ unsigned pack2bf(float x, float y) {
    return ((unsigned)f2bf(x)) | ((unsigned)f2bf(y) << 16);
}

// ---------------------------------------------------------------------------
// CSR build step 1: histogram of dst (counts pre-zeroed).
// ---------------------------------------------------------------------------
__global__ __launch_bounds__(256) void hist_kernel(
    const int* __restrict__ dst, int* __restrict__ counts)
{
    int e = blockIdx.x * 256 + threadIdx.x;
    atomicAdd(&counts[dst[e]], 1);
}

// ---------------------------------------------------------------------------
// CSR build step 2: exclusive scan -> offsets[N_NODES+1] + cursor copy.
// ---------------------------------------------------------------------------
__global__ __launch_bounds__(1024) void scan_kernel(
    const int* __restrict__ counts, int* __restrict__ offsets,
    int* __restrict__ cursor)
{
    __shared__ int part[1024];
    const int t = threadIdx.x;
    const int CH = (N_NODES + 1023) / 1024;   // 49
    const int lo = t * CH;
    const int hi = (lo + CH < N_NODES) ? lo + CH : N_NODES;
    int s = 0;
    for (int i = lo; i < hi; ++i) s += counts[i];
    part[t] = s;
    __syncthreads();
    for (int off = 1; off < 1024; off <<= 1) {
        int v = (t >= off) ? part[t - off] : 0;
        __syncthreads();
        part[t] += v;
        __syncthreads();
    }
    int run = (t > 0) ? part[t - 1] : 0;
    for (int i = lo; i < hi; ++i) {
        offsets[i] = run;
        cursor[i]  = run;
        run += counts[i];
    }
    if (t == 1023) offsets[N_NODES] = run;
}

// ---------------------------------------------------------------------------
// CSR build step 3: scatter edges into dst-sorted order; edge_attr -> bf16
// (16 bf16 = 32B per edge, MFMA-ready A-operand rows).
// ---------------------------------------------------------------------------
__global__ __launch_bounds__(256) void scatter_kernel(
    const int* __restrict__ src, const int* __restrict__ dst,
    const float* __restrict__ edge_attr,
    int* __restrict__ cursor, int* __restrict__ sorted_src,
    uint4* __restrict__ sorted_eab)
{
    int e = blockIdx.x * 256 + threadIdx.x;
    int d = dst[e];
    int pos = atomicAdd(&cursor[d], 1);
    sorted_src[pos] = src[e];
    const float4* ea = (const float4*)(edge_attr + (size_t)e * EF);
    float4 a0 = ea[0], a1 = ea[1], a2 = ea[2], a3 = ea[3];
    uint4 o0, o1;
    o0.x = pack2bf(a0.x, a0.y); o0.y = pack2bf(a0.z, a0.w);
    o0.z = pack2bf(a1.x, a1.y); o0.w = pack2bf(a1.z, a1.w);
    o1.x = pack2bf(a2.x, a2.y); o1.y = pack2bf(a2.z, a2.w);
    o1.z = pack2bf(a3.x, a3.y); o1.w = pack2bf(a3.z, a3.w);
    sorted_eab[(size_t)pos * 2]     = o0;
    sorted_eab[(size_t)pos * 2 + 1] = o1;
}

// ---------------------------------------------------------------------------
// Graph offsets: batch is sorted; goff[g] = lower_bound(batch, g), goff[512]=N.
// ---------------------------------------------------------------------------
__global__ __launch_bounds__(512) void goff_kernel(
    const int* __restrict__ batch, int* __restrict__ goff)
{
    const int g = threadIdx.x;
    int lo = 0, hi = N_NODES;
    while (lo < hi) {
        int mid = (lo + hi) >> 1;
        if (batch[mid] < g) lo = mid + 1; else hi = mid;
    }
    goff[g] = lo;
    if (g == 0) goff[N_GRAPHS] = N_NODES;
}

// ---------------------------------------------------------------------------
// Weight prep: transpose W1/W2 (all layers) to bf16 Wt[out][k], once per call.
// ---------------------------------------------------------------------------
__global__ __launch_bounds__(256) void wprep_kernel(
    const float* __restrict__ W1, const float* __restrict__ W2,
    unsigned short* __restrict__ Wt)
{
    const int matid = blockIdx.x;          // l*2 + (0:W1, 1:W2)
    const int l = matid >> 1;
    const float* srcm = (matid & 1) ? (W2 + (size_t)l * D * D)
                                    : (W1 + (size_t)l * D * D);
    unsigned short* out = Wt + (size_t)matid * D * D;
    for (int i = 0; i < 64; ++i) {
        int idx = threadIdx.x + i * 256;
        int k = idx >> 7, n = idx & 127;
        out[n * D + k] = f2bf(srcm[idx]);
    }
}

// ---------------------------------------------------------------------------
// elW prep: B-fragment-ordered bf16 copy of elW per layer.
// elWb[l][t][q][m][j] = bf16(elW[l][q*8+j][t*16+m]), q<2 (k=q*8+j covers 0..15)
// Flat index: l*2048 + t*256 + q*128 + m*8 + j. 4 KB per layer.
// ---------------------------------------------------------------------------
__global__ __launch_bounds__(256) void eprep_kernel(
    const float* __restrict__ elW, unsigned short* __restrict__ elWb)
{
    const int l = blockIdx.x;
    const float* w = elW + (size_t)l * EF * D;
    unsigned short* o = elWb + (size_t)l * 2048;
    for (int i = threadIdx.x; i < 2048; i += 256) {
        int j  = i & 7;
        int mm = (i >> 3) & 15;
        int qq = (i >> 7) & 1;
        int t  = i >> 8;
        o[i] = f2bf(w[(qq * 8 + j) * D + (t * 16 + mm)]);
    }
}

// ---------------------------------------------------------------------------
// x -> bf16 (once per call).
// ---------------------------------------------------------------------------
__global__ __launch_bounds__(256) void xprep_kernel(
    const float* __restrict__ x, unsigned short* __restrict__ xb)
{
    int i = blockIdx.x * 256 + threadIdx.x;   // grid exact: 6.4M/256
    xb[i] = f2bf(x[i]);
}

// ---------------------------------------------------------------------------
// Per-layer aggregation via MFMA (gather, no atomics, no LDS):
//   zin_b[n][:] = bf16( h[n] + sum_e relu(h[src_e] + ea_e@elW + elb) )
// One wave per node (4 nodes / 256-thr block). Per 16-edge batch:
//   E16 = mfma(A=ea[16][16 pad 32], B=elW tile, C=elb)  -- 8 tiles of 16 cols
//   then VALU: relu(h[src_row][col] + E16) summed over the 16 edge rows.
// Layouts as verified in node_mlp: A[m=lane&15][k=q*8+j], B[k=q*8+j][n=lane&15],
// C/D row=q*4+reg, col=lane&15. K=16..31 zero-padded (A and B zero for q>=2).
// ---------------------------------------------------------------------------
__global__ __launch_bounds__(256) void aggr_kernel(
    const unsigned short* __restrict__ h_b,     // [N][128] bf16
    const unsigned short* __restrict__ ea_b,    // [E][16] bf16
    const int*   __restrict__ sorted_src,
    const int*   __restrict__ offsets,
    const unsigned short* __restrict__ elWb,    // [8][2][16][8] bf16 this layer
    const float* __restrict__ elb,              // [128] fp32
    unsigned short* __restrict__ zin_b)
{
    const int lane = threadIdx.x & 63;
    const int wv   = threadIdx.x >> 6;
    const int n    = blockIdx.x * 4 + wv;       // grid exact: 50000/4
    const int q    = lane >> 4;
    const int m    = lane & 15;

    // B-fragments (per tile): one uint4 from elWb for q<2, zero for q>=2.
    bf16x8 bfr[8];
    #pragma unroll
    for (int t = 0; t < 8; ++t) {
        bf16x8 z = (bf16x8){0,0,0,0,0,0,0,0};
        if (q < 2)
            z = __builtin_bit_cast(bf16x8,
                    *(const uint4*)&elWb[(size_t)((t * 2 + q) * 16 + m) * 8]);
        bfr[t] = z;
    }
    float eb[8];
    #pragma unroll
    for (int t = 0; t < 8; ++t) eb[t] = elb[t * 16 + m];

    const int beg = offsets[n];
    const int end = offsets[n + 1];

    float facc[8];
    #pragma unroll
    for (int t = 0; t < 8; ++t) facc[t] = 0.f;

    int base = beg;
    // ---- full 16-edge batches ----
    for (; base + 16 <= end; base += 16) {
        bf16x8 afr = (bf16x8){0,0,0,0,0,0,0,0};
        if (q < 2)
            afr = __builtin_bit_cast(bf16x8,
                    *(const uint4*)&ea_b[(size_t)(base + m) * 16 + q * 8]);
        const int s0 = sorted_src[base + q * 4 + 0];
        const int s1 = sorted_src[base + q * 4 + 1];
        const int s2 = sorted_src[base + q * 4 + 2];
        const int s3 = sorted_src[base + q * 4 + 3];
        #pragma unroll
        for (int t = 0; t < 8; ++t) {
            f32x4 c = (f32x4){eb[t], eb[t], eb[t], eb[t]};
            c = __builtin_amdgcn_mfma_f32_16x16x32_bf16(afr, bfr[t], c, 0, 0, 0);
            const int col = t * 16 + m;
            float v0 = fmaxf(bf2f(h_b[(size_t)s0 * D + col]) + c[0], 0.f);
            float v1 = fmaxf(bf2f(h_b[(size_t)s1 * D + col]) + c[1], 0.f);
            float v2 = fmaxf(bf2f(h_b[(size_t)s2 * D + col]) + c[2], 0.f);
            float v3 = fmaxf(bf2f(h_b[(size_t)s3 * D + col]) + c[3], 0.f);
            facc[t] += (v0 + v1) + (v2 + v3);
        }
    }
    // ---- partial batch (1..15 edges): index-clamped loads, masked adds ----
    const int rem = end - base;
    if (rem > 0) {
        const int eidx = base + (m < rem ? m : rem - 1);
        bf16x8 afr = (bf16x8){0,0,0,0,0,0,0,0};
        if (q < 2)
            afr = __builtin_bit_cast(bf16x8,
                    *(const uint4*)&ea_b[(size_t)eidx * 16 + q * 8]);
        const int r0 = q * 4;
        const int s0 = sorted_src[base + (r0 + 0 < rem ? r0 + 0 : rem - 1)];
        const int s1 = sorted_src[base + (r0 + 1 < rem ? r0 + 1 : rem - 1)];
        const int s2 = sorted_src[base + (r0 + 2 < rem ? r0 + 2 : rem - 1)];
        const int s3 = sorted_src[base + (r0 + 3 < rem ? r0 + 3 : rem - 1)];
        #pragma unroll
        for (int t = 0; t < 8; ++t) {
            f32x4 c = (f32x4){eb[t], eb[t], eb[t], eb[t]};
            c = __builtin_amdgcn_mfma_f32_16x16x32_bf16(afr, bfr[t], c, 0, 0, 0);
            const int col = t * 16 + m;
            float v0 = fmaxf(bf2f(h_b[(size_t)s0 * D + col]) + c[0], 0.f);
            float v1 = fmaxf(bf2f(h_b[(size_t)s1 * D + col]) + c[1], 0.f);
            float v2 = fmaxf(bf2f(h_b[(size_t)s2 * D + col]) + c[2], 0.f);
            float v3 = fmaxf(bf2f(h_b[(size_t)s3 * D + col]) + c[3], 0.f);
            v0 = (r0 + 0 < rem) ? v0 : 0.f;
            v1 = (r0 + 1 < rem) ? v1 : 0.f;
            v2 = (r0 + 2 < rem) ? v2 : 0.f;
            v3 = (r0 + 3 < rem) ? v3 : 0.f;
            facc[t] += (v0 + v1) + (v2 + v3);
        }
    }

    // ---- reduce edge-rows across quads; all lanes end with the full sum ----
    #pragma unroll
    for (int t = 0; t < 8; ++t) {
        float s = facc[t];
        s += __shfl_xor(s, 16, 64);
        s += __shfl_xor(s, 32, 64);
        facc[t] = s;
    }
    // ---- add self h, write zin (quad 0 lanes write all 8 tiles) ----
    if (q == 0) {
        #pragma unroll
        for (int t = 0; t < 8; ++t) {
            const int col = t * 16 + m;
            zin_b[(size_t)n * D + col] =
                f2bf(bf2f(h_b[(size_t)n * D + col]) + facc[t]);
        }
    }
}

// ---------------------------------------------------------------------------
// Fused node MLP via MFMA (bf16 in, fp32 accumulate):
//   hout_b = bf16(relu(relu(BN(zin@W1+b1))@W2 + b2))
// 128 threads = 2 waves, 64 nodes/block; B-frags from global (L2-resident).
// ---------------------------------------------------------------------------
__global__ __launch_bounds__(128) void node_mlp(
    const unsigned short* __restrict__ zin_b,   // [N][128] bf16
    const unsigned short* __restrict__ W1t,     // [128 out][128 k] bf16
    const float* __restrict__ b1,
    const float* __restrict__ bng, const float* __restrict__ bnb,
    const float* __restrict__ bnm, const float* __restrict__ bnv,
    const unsigned short* __restrict__ W2t,
    const float* __restrict__ b2,
    unsigned short* __restrict__ hout_b)
{
    __shared__ unsigned short zmid[64 * 136];   // 17.4 KB
    __shared__ float scale_s[128], shift_s[128], b2_s[128];

    const int tid  = threadIdx.x;
    const int wv   = tid >> 6;        // 0..1
    const int lane = tid & 63;
    const int q    = lane >> 4;
    const int m    = lane & 15;
    const int node0 = blockIdx.x * 64;

    {
        float sc = bng[tid] * rsqrtf(bnv[tid] + BN_EPS);
        scale_s[tid] = sc;
        shift_s[tid] = b1[tid] * sc + bnb[tid] - bnm[tid] * sc;  // fold b1 into BN
        b2_s[tid]    = b2[tid];
    }

    // A fragments straight from global bf16 zin
    bf16x8 a[2][4];
    #pragma unroll
    for (int sub = 0; sub < 2; ++sub) {
        int node = node0 + wv * 32 + sub * 16 + m;
        if (node >= N_NODES) node = N_NODES - 1;
        const uint4* zrow = (const uint4*)(zin_b + (size_t)node * D);
        #pragma unroll
        for (int k = 0; k < 4; ++k)
            a[sub][k] = __builtin_bit_cast(bf16x8, zrow[k * 4 + q]);
    }

    f32x4 acc[2][8];
    #pragma unroll
    for (int s2 = 0; s2 < 2; ++s2)
        #pragma unroll
        for (int t = 0; t < 8; ++t)
            acc[s2][t] = (f32x4){0.f, 0.f, 0.f, 0.f};

    __syncthreads();   // scale_s/shift_s ready

    // GEMM 1: B-frags from global W1t
    #pragma unroll
    for (int t = 0; t < 8; ++t) {
        const unsigned short* wrow = W1t + (size_t)(t * 16 + m) * D;
        bf16x8 bfr[4];
        #pragma unroll
        for (int k = 0; k < 4; ++k)
            bfr[k] = __builtin_bit_cast(bf16x8, *(const uint4*)&wrow[k * 32 + q * 8]);
        #pragma unroll
        for (int sub = 0; sub < 2; ++sub) {
            acc[sub][t] = __builtin_amdgcn_mfma_f32_16x16x32_bf16(a[sub][0], bfr[0], acc[sub][t], 0, 0, 0);
            acc[sub][t] = __builtin_amdgcn_mfma_f32_16x16x32_bf16(a[sub][1], bfr[1], acc[sub][t], 0, 0, 0);
            acc[sub][t] = __builtin_amdgcn_mfma_f32_16x16x32_bf16(a[sub][2], bfr[2], acc[sub][t], 0, 0, 0);
            acc[sub][t] = __builtin_amdgcn_mfma_f32_16x16x32_bf16(a[sub][3], bfr[3], acc[sub][t], 0, 0, 0);
        }
    }

    // epilogue 1: BN + relu -> zmid (bf16, C/D layout -> LDS)
    #pragma unroll
    for (int sub = 0; sub < 2; ++sub)
        #pragma unroll
        for (int t = 0; t < 8; ++t) {
            int col = t * 16 + m;
            float sc = scale_s[col], sh = shift_s[col];
            #pragma unroll
            for (int rr = 0; rr < 4; ++rr) {
                float v = fmaxf(acc[sub][t][rr] * sc + sh, 0.f);
                int row = wv * 32 + sub * 16 + q * 4 + rr;
                zmid[row * 136 + col] = f2bf(v);
            }
        }

    __syncthreads();   // zmid complete

    // A2 frags from zmid
    bf16x8 a2[2][4];
    #pragma unroll
    for (int sub = 0; sub < 2; ++sub) {
        const unsigned short* zr = &zmid[(wv * 32 + sub * 16 + m) * 136];
        #pragma unroll
        for (int k = 0; k < 4; ++k)
            a2[sub][k] = __builtin_bit_cast(bf16x8, *(const uint4*)&zr[k * 32 + q * 8]);
    }

    #pragma unroll
    for (int s2 = 0; s2 < 2; ++s2)
        #pragma unroll
        for (int t = 0; t < 8; ++t)
            acc[s2][t] = (f32x4){0.f, 0.f, 0.f, 0.f};

    // GEMM 2: B-frags from global W2t
    #pragma unroll
    for (int t = 0; t < 8; ++t) {
        const unsigned short* wrow = W2t + (size_t)(t * 16 + m) * D;
        bf16x8 bfr[4];
        #pragma unroll
        for (int k = 0; k < 4; ++k)
            bfr[k] = __builtin_bit_cast(bf16x8, *(const uint4*)&wrow[k * 32 + q * 8]);
        #pragma unroll
        for (int sub = 0; sub < 2; ++sub) {
            acc[sub][t] = __builtin_amdgcn_mfma_f32_16x16x32_bf16(a2[sub][0], bfr[0], acc[sub][t], 0, 0, 0);
            acc[sub][t] = __builtin_amdgcn_mfma_f32_16x16x32_bf16(a2[sub][1], bfr[1], acc[sub][t], 0, 0, 0);
            acc[sub][t] = __builtin_amdgcn_mfma_f32_16x16x32_bf16(a2[sub][2], bfr[2], acc[sub][t], 0, 0, 0);
            acc[sub][t] = __builtin_amdgcn_mfma_f32_16x16x32_bf16(a2[sub][3], bfr[3], acc[sub][t], 0, 0, 0);
        }
    }

    // epilogue 2: bias + relu -> hout (bf16). No atomics.
    #pragma unroll
    for (int sub = 0; sub < 2; ++sub)
        #pragma unroll
        for (int rr = 0; rr < 4; ++rr) {
            int node = node0 + wv * 32 + sub * 16 + q * 4 + rr;
            if (node < N_NODES) {
                unsigned short* hrow = hout_b + (size_t)node * D;
                #pragma unroll
                for (int t = 0; t < 8; ++t) {
                    int col = t * 16 + m;
                    hrow[col] = f2bf(fmaxf(acc[sub][t][rr] + b2_s[col], 0.f));
                }
            }
        }
}

// ---------------------------------------------------------------------------
// Pool: segmented sum over sorted batch (bf16 in, fp32 out). No atomics.
// ---------------------------------------------------------------------------
__global__ __launch_bounds__(128) void pool_kernel(
    const unsigned short* __restrict__ hout_b, const int* __restrict__ goff,
    float* __restrict__ pool, int layer_off)
{
    const int g = blockIdx.x;
    const int j = threadIdx.x;
    const int beg = goff[g], end = goff[g + 1];
    float acc = 0.0f;
    for (int r = beg; r < end; ++r)
        acc += bf2f(hout_b[(size_t)r * D + j]);
    pool[g * (LAYERS * D) + layer_off + j] = acc;
}

// ---------------------------------------------------------------------------
// Head: out[g] = relu(pool[g] @ lin1_W + lin1_b) @ lin2_W + lin2_b
// ---------------------------------------------------------------------------
__global__ __launch_bounds__(384) void head_kernel(
    const float* __restrict__ pool,
    const float* __restrict__ lin1W,
    const float* __restrict__ lin1b,
    const float* __restrict__ lin2W,
    const float* __restrict__ lin2b,
    float*       __restrict__ out)
{
    __shared__ float gs[LAYERS * D];
    __shared__ float red[LAYERS * D];
    const int g   = blockIdx.x;
    const int tid = threadIdx.x;
    gs[tid] = pool[g * (LAYERS * D) + tid];
    __syncthreads();

    float acc = lin1b[tid];
    #pragma unroll 4
    for (int k = 0; k < LAYERS * D; ++k)
        acc = fmaf(gs[k], lin1W[k * (LAYERS * D) + tid], acc);
    acc = fmaxf(acc, 0.0f);
    float p = acc * lin2W[tid];

    red[tid] = p;
    __syncthreads();
    if (tid < 128) red[tid] = red[tid] + red[tid + 128] + red[tid + 256];
    __syncthreads();
    if (tid < 64) {
        float v = red[tid] + red[tid + 64];
        v += __shfl_down(v, 32);
        v += __shfl_down(v, 16);
        v += __shfl_down(v, 8);
        v += __shfl_down(v, 4);
        v += __shfl_down(v, 2);
        v += __shfl_down(v, 1);
        if (tid == 0) out[g] = v + lin2b[0];
    }
}

// ---------------------------------------------------------------------------
extern "C" void kernel_launch(void* const* d_in, const int* in_sizes, int n_in,
                              void* d_out, int out_size, void* d_ws, size_t ws_size,
                              hipStream_t stream)
{
    const float* x         = (const float*)d_in[0];
    const float* edge_attr = (const float*)d_in[1];
    const float* elW       = (const float*)d_in[2];
    const float* elb       = (const float*)d_in[3];
    const float* W1        = (const float*)d_in[4];
    const float* b1        = (const float*)d_in[5];
    const float* bn_g      = (const float*)d_in[6];
    const float* bn_b      = (const float*)d_in[7];
    const float* bn_mean   = (const float*)d_in[8];
    const float* bn_var    = (const float*)d_in[9];
    const float* W2        = (const float*)d_in[10];
    const float* b2        = (const float*)d_in[11];
    const float* lin1W     = (const float*)d_in[12];
    const float* lin1b     = (const float*)d_in[13];
    const float* lin2W     = (const float*)d_in[14];
    const float* lin2b     = (const float*)d_in[15];
    const int*   ei        = (const int*)d_in[16];
    const int*   batch     = (const int*)d_in[17];
    const int*   src = ei;
    const int*   dst = ei + N_EDGES;

    // Workspace layout, all 16B-aligned:
    float*          pool       = (float*)d_ws;                              // G*384 f32
    unsigned short* xb         = (unsigned short*)(pool + (size_t)N_GRAPHS * LAYERS * D);
    unsigned short* hA_b       = xb   + (size_t)N_NODES * D;                // bf16
    unsigned short* zin_b      = hA_b + (size_t)N_NODES * D;                // bf16
    unsigned short* Wt         = zin_b + (size_t)N_NODES * D;               // 6*16384 bf16
    unsigned short* elWb       = Wt + 6 * D * D;                            // 3*2048 bf16
    unsigned short* pad        = elWb + 3 * 2048;                           // keep 16B align
    unsigned*       sorted_eab = (unsigned*)pad;                            // E*8 u32
    int*            sorted_src = (int*)(sorted_eab + (size_t)N_EDGES * 8);
    int*            counts     = sorted_src + N_EDGES;
    int*            offsets    = counts + N_NODES;
    int*            cursor     = offsets + N_NODES + 4;
    int*            goff       = cursor + N_NODES + 4;                      // 513 ints

    hipMemsetAsync(counts, 0, (size_t)N_NODES * sizeof(int), stream);

    // --- once-per-call prep ---
    wprep_kernel<<<6, 256, 0, stream>>>(W1, W2, Wt);
    eprep_kernel<<<LAYERS, 256, 0, stream>>>(elW, elWb);
    xprep_kernel<<<(N_NODES * D) / 256, 256, 0, stream>>>(x, xb);
    goff_kernel<<<1, 512, 0, stream>>>(batch, goff);
    hist_kernel<<<N_EDGES / 256, 256, 0, stream>>>(dst, counts);
    scan_kernel<<<1, 1024, 0, stream>>>(counts, offsets, cursor);
    scatter_kernel<<<N_EDGES / 256, 256, 0, stream>>>(
        src, dst, edge_attr, cursor, sorted_src, (uint4*)sorted_eab);

    const unsigned short* hin_b = xb;
    for (int l = 0; l < LAYERS; ++l) {
        aggr_kernel<<<N_NODES / 4, 256, 0, stream>>>(
            hin_b, (const unsigned short*)sorted_eab, sorted_src, offsets,
            elWb + (size_t)l * 2048, elb + l * D, zin_b);
        node_mlp<<<(N_NODES + 63) / 64, 128, 0, stream>>>(
            zin_b,
            Wt + (size_t)(l * 2)     * D * D, b1 + l * D,
            bn_g + l * D, bn_b + l * D, bn_mean + l * D, bn_var + l * D,
            Wt + (size_t)(l * 2 + 1) * D * D, b2 + l * D,
            hA_b);
        pool_kernel<<<N_GRAPHS, 128, 0, stream>>>(hA_b, goff, pool, l * D);
        hin_b = hA_b;
    }

    head_kernel<<<N_GRAPHS, LAYERS * D, 0, stream>>>(
        pool, lin1W, lin1b, lin2W, lin2b, (float*)d_out);
}

// Round 8
// 922.027 us; speedup vs baseline: 1.4924x; 1.4924x over previous
//
#include <hip/hip_runtime.h>

#define N_NODES   50000
#define N_EDGES   1600000
#define N_GRAPHS  512
#define LAYERS    3
#define D         128
#define EF        16
#define BN_EPS    1e-5f

typedef _Float16 half2v __attribute__((ext_vector_type(2)));
typedef short bf16x8 __attribute__((ext_vector_type(8)));
typedef float f32x4 __attribute__((ext_vector_type(4)));

__device__ __forceinline__ float fdot2h(unsigned a, half2v b, float c) {
#if __has_builtin(__builtin_amdgcn_fdot2)
    return __builtin_amdgcn_fdot2(__builtin_bit_cast(half2v, a), b, c, false);
#else
    half2v av = __builtin_bit_cast(half2v, a);
    return fmaf((float)av[0], (float)b[0], fmaf((float)av[1], (float)b[1], c));
#endif
}

__device__ __forceinline__ unsigned pack_h2(float x, float y) {
    half2v t; t[0] = (_Float16)x; t[1] = (_Float16)y;
    return __builtin_bit_cast(unsigned, t);
}

__device__ __forceinline__ unsigned short f2bf(float f) {   // RNE f32->bf16
    unsigned u = __builtin_bit_cast(unsigned, f);
    u += 0x7FFF + ((u >> 16) & 1);
    return (unsigned short)(u >> 16);
}

__device__ __forceinline__ float bf2f(unsigned short u) {
    return __builtin_bit_cast(float, (unsigned)u << 16);
}

// ---------------------------------------------------------------------------
// CSR build step 1: histogram of dst (counts pre-zeroed).
// ---------------------------------------------------------------------------
__global__ __launch_bounds__(256) void hist_kernel(
    const int* __restrict__ dst, int* __restrict__ counts)
{
    int e = blockIdx.x * 256 + threadIdx.x;
    atomicAdd(&counts[dst[e]], 1);
}

// ---------------------------------------------------------------------------
// CSR build step 2: exclusive scan -> offsets[N_NODES+1] + cursor copy.
// ---------------------------------------------------------------------------
__global__ __launch_bounds__(1024) void scan_kernel(
    const int* __restrict__ counts, int* __restrict__ offsets,
    int* __restrict__ cursor)
{
    __shared__ int part[1024];
    const int t = threadIdx.x;
    const int CH = (N_NODES + 1023) / 1024;   // 49
    const int lo = t * CH;
    const int hi = (lo + CH < N_NODES) ? lo + CH : N_NODES;
    int s = 0;
    for (int i = lo; i < hi; ++i) s += counts[i];
    part[t] = s;
    __syncthreads();
    for (int off = 1; off < 1024; off <<= 1) {
        int v = (t >= off) ? part[t - off] : 0;
        __syncthreads();
        part[t] += v;
        __syncthreads();
    }
    int run = (t > 0) ? part[t - 1] : 0;
    for (int i = lo; i < hi; ++i) {
        offsets[i] = run;
        cursor[i]  = run;
        run += counts[i];
    }
    if (t == 1023) offsets[N_NODES] = run;
}

// ---------------------------------------------------------------------------
// CSR build step 3: scatter edges into dst-sorted order; edge_attr -> f16
// (8 half2 = 32B per edge; dot2-ready).
// ---------------------------------------------------------------------------
__global__ __launch_bounds__(256) void scatter_kernel(
    const int* __restrict__ src, const int* __restrict__ dst,
    const float* __restrict__ edge_attr,
    int* __restrict__ cursor, int* __restrict__ sorted_src,
    uint4* __restrict__ sorted_eah)
{
    int e = blockIdx.x * 256 + threadIdx.x;
    int d = dst[e];
    int pos = atomicAdd(&cursor[d], 1);
    sorted_src[pos] = src[e];
    const float4* ea = (const float4*)(edge_attr + (size_t)e * EF);
    float4 a0 = ea[0], a1 = ea[1], a2 = ea[2], a3 = ea[3];
    uint4 o0, o1;
    o0.x = pack_h2(a0.x, a0.y); o0.y = pack_h2(a0.z, a0.w);
    o0.z = pack_h2(a1.x, a1.y); o0.w = pack_h2(a1.z, a1.w);
    o1.x = pack_h2(a2.x, a2.y); o1.y = pack_h2(a2.z, a2.w);
    o1.z = pack_h2(a3.x, a3.y); o1.w = pack_h2(a3.z, a3.w);
    sorted_eah[(size_t)pos * 2]     = o0;
    sorted_eah[(size_t)pos * 2 + 1] = o1;
}

// ---------------------------------------------------------------------------
// Graph offsets: batch is sorted; goff[g] = lower_bound(batch, g), goff[512]=N.
// ---------------------------------------------------------------------------
__global__ __launch_bounds__(512) void goff_kernel(
    const int* __restrict__ batch, int* __restrict__ goff)
{
    const int g = threadIdx.x;
    int lo = 0, hi = N_NODES;
    while (lo < hi) {
        int mid = (lo + hi) >> 1;
        if (batch[mid] < g) lo = mid + 1; else hi = mid;
    }
    goff[g] = lo;
    if (g == 0) goff[N_GRAPHS] = N_NODES;
}

// ---------------------------------------------------------------------------
// Weight prep: transpose W1/W2 (all layers) to bf16 Wt[out][k], once per call.
// ---------------------------------------------------------------------------
__global__ __launch_bounds__(256) void wprep_kernel(
    const float* __restrict__ W1, const float* __restrict__ W2,
    unsigned short* __restrict__ Wt)
{
    const int matid = blockIdx.x;          // l*2 + (0:W1, 1:W2)
    const int l = matid >> 1;
    const float* srcm = (matid & 1) ? (W2 + (size_t)l * D * D)
                                    : (W1 + (size_t)l * D * D);
    unsigned short* out = Wt + (size_t)matid * D * D;
    for (int i = 0; i < 64; ++i) {
        int idx = threadIdx.x + i * 256;
        int k = idx >> 7, n = idx & 127;
        out[n * D + k] = f2bf(srcm[idx]);
    }
}

// ---------------------------------------------------------------------------
// x -> bf16 (once per call).
// ---------------------------------------------------------------------------
__global__ __launch_bounds__(256) void xprep_kernel(
    const float* __restrict__ x, unsigned short* __restrict__ xb)
{
    int i = blockIdx.x * 256 + threadIdx.x;   // grid exact: 6.4M/256
    xb[i] = f2bf(x[i]);
}

// ---------------------------------------------------------------------------
// Per-layer aggregation v3 (gather, no atomics):
//   zin_b[n][:] = bf16( h[n] + sum_e relu(h[src_e] + ea_e@elW + elb) )
// One 128-thr block per node. The 2 waves split the CSR row (halves), each
// lane owns 2 features (j0=2*lane, j0+1): one dword h-load per edge, two
// independent 8-deep dot2 chains, scalar (s_load) edge data once per edge.
// LDS float2 combine at the end.
// ---------------------------------------------------------------------------
__global__ __launch_bounds__(128) void aggr_kernel(
    const unsigned short* __restrict__ h_b,    // [N][128] bf16
    const uint4* __restrict__ sorted_ea,       // 2 x uint4 per edge (f16x16)
    const int*   __restrict__ sorted_src,
    const int*   __restrict__ offsets,
    const float* __restrict__ elW,   // [16][128] this layer
    const float* __restrict__ elb,
    unsigned* __restrict__ zin_b)              // [N][64] packed bf16x2
{
    const int lane = threadIdx.x & 63;
    const int wv   = __builtin_amdgcn_readfirstlane(threadIdx.x >> 6); // SGPR
    const int n    = blockIdx.x;
    const int j0   = lane * 2;

    half2v wA[8], wB[8];
    #pragma unroll
    for (int k = 0; k < 8; ++k) {
        half2v ta, tb;
        ta[0] = (_Float16)elW[(2*k    ) * D + j0];
        ta[1] = (_Float16)elW[(2*k + 1) * D + j0];
        tb[0] = (_Float16)elW[(2*k    ) * D + j0 + 1];
        tb[1] = (_Float16)elW[(2*k + 1) * D + j0 + 1];
        wA[k] = ta; wB[k] = tb;
    }
    const float biasA = elb[j0];
    const float biasB = elb[j0 + 1];

    const int beg = offsets[n];
    const int end = offsets[n + 1];
    const int cnt = end - beg;
    const int h0  = (cnt + 1) >> 1;
    const int lo  = wv ? beg + h0 : beg;
    const int hi  = wv ? end : beg + h0;

    float accA = 0.0f, accB = 0.0f;
    #pragma unroll 2
    for (int e = lo; e < hi; ++e) {
        const uint4 p0 = sorted_ea[(size_t)e * 2];      // uniform -> s_load
        const uint4 p1 = sorted_ea[(size_t)e * 2 + 1];  // uniform -> s_load
        const int   s  = sorted_src[e];                 // uniform -> s_load
        const unsigned hv2 = *(const unsigned*)(h_b + (size_t)s * D + j0);
        float dA = biasA, dB = biasB;
        dA = fdot2h(p0.x, wA[0], dA);  dB = fdot2h(p0.x, wB[0], dB);
        dA = fdot2h(p0.y, wA[1], dA);  dB = fdot2h(p0.y, wB[1], dB);
        dA = fdot2h(p0.z, wA[2], dA);  dB = fdot2h(p0.z, wB[2], dB);
        dA = fdot2h(p0.w, wA[3], dA);  dB = fdot2h(p0.w, wB[3], dB);
        dA = fdot2h(p1.x, wA[4], dA);  dB = fdot2h(p1.x, wB[4], dB);
        dA = fdot2h(p1.y, wA[5], dA);  dB = fdot2h(p1.y, wB[5], dB);
        dA = fdot2h(p1.z, wA[6], dA);  dB = fdot2h(p1.z, wB[6], dB);
        dA = fdot2h(p1.w, wA[7], dA);  dB = fdot2h(p1.w, wB[7], dB);
        const float hA = __builtin_bit_cast(float, hv2 << 16);
        const float hB = __builtin_bit_cast(float, hv2 & 0xFFFF0000u);
        accA += fmaxf(hA + dA, 0.0f);
        accB += fmaxf(hB + dB, 0.0f);
    }

    __shared__ float2 part2[64];
    if (wv == 1) part2[lane] = make_float2(accA, accB);
    __syncthreads();
    if (wv == 0) {
        float2 p = part2[lane];
        const unsigned hs2 = *(const unsigned*)(h_b + (size_t)n * D + j0);
        const float hA = __builtin_bit_cast(float, hs2 << 16);
        const float hB = __builtin_bit_cast(float, hs2 & 0xFFFF0000u);
        const float a = hA + accA + p.x;
        const float b = hB + accB + p.y;
        zin_b[(size_t)n * 64 + lane] =
            ((unsigned)f2bf(a)) | ((unsigned)f2bf(b) << 16);
    }
}

// ---------------------------------------------------------------------------
// Fused node MLP via MFMA (bf16 in, fp32 accumulate):
//   hout_b = bf16(relu(relu(BN(zin@W1+b1))@W2 + b2))
// 128 threads = 2 waves, 64 nodes/block; B-frags from global (L2-resident).
// ---------------------------------------------------------------------------
__global__ __launch_bounds__(128) void node_mlp(
    const unsigned short* __restrict__ zin_b,   // [N][128] bf16
    const unsigned short* __restrict__ W1t,     // [128 out][128 k] bf16
    const float* __restrict__ b1,
    const float* __restrict__ bng, const float* __restrict__ bnb,
    const float* __restrict__ bnm, const float* __restrict__ bnv,
    const unsigned short* __restrict__ W2t,
    const float* __restrict__ b2,
    unsigned short* __restrict__ hout_b)
{
    __shared__ unsigned short zmid[64 * 136];   // 17.4 KB
    __shared__ float scale_s[128], shift_s[128], b2_s[128];

    const int tid  = threadIdx.x;
    const int wv   = tid >> 6;        // 0..1
    const int lane = tid & 63;
    const int q    = lane >> 4;
    const int m    = lane & 15;
    const int node0 = blockIdx.x * 64;

    {
        float sc = bng[tid] * rsqrtf(bnv[tid] + BN_EPS);
        scale_s[tid] = sc;
        shift_s[tid] = b1[tid] * sc + bnb[tid] - bnm[tid] * sc;  // fold b1 into BN
        b2_s[tid]    = b2[tid];
    }

    // A fragments straight from global bf16 zin
    bf16x8 a[2][4];
    #pragma unroll
    for (int sub = 0; sub < 2; ++sub) {
        int node = node0 + wv * 32 + sub * 16 + m;
        if (node >= N_NODES) node = N_NODES - 1;
        const uint4* zrow = (const uint4*)(zin_b + (size_t)node * D);
        #pragma unroll
        for (int k = 0; k < 4; ++k)
            a[sub][k] = __builtin_bit_cast(bf16x8, zrow[k * 4 + q]);
    }

    f32x4 acc[2][8];
    #pragma unroll
    for (int s2 = 0; s2 < 2; ++s2)
        #pragma unroll
        for (int t = 0; t < 8; ++t)
            acc[s2][t] = (f32x4){0.f, 0.f, 0.f, 0.f};

    __syncthreads();   // scale_s/shift_s ready

    // GEMM 1: B-frags from global W1t
    #pragma unroll
    for (int t = 0; t < 8; ++t) {
        const unsigned short* wrow = W1t + (size_t)(t * 16 + m) * D;
        bf16x8 bfr[4];
        #pragma unroll
        for (int k = 0; k < 4; ++k)
            bfr[k] = __builtin_bit_cast(bf16x8, *(const uint4*)&wrow[k * 32 + q * 8]);
        #pragma unroll
        for (int sub = 0; sub < 2; ++sub) {
            acc[sub][t] = __builtin_amdgcn_mfma_f32_16x16x32_bf16(a[sub][0], bfr[0], acc[sub][t], 0, 0, 0);
            acc[sub][t] = __builtin_amdgcn_mfma_f32_16x16x32_bf16(a[sub][1], bfr[1], acc[sub][t], 0, 0, 0);
            acc[sub][t] = __builtin_amdgcn_mfma_f32_16x16x32_bf16(a[sub][2], bfr[2], acc[sub][t], 0, 0, 0);
            acc[sub][t] = __builtin_amdgcn_mfma_f32_16x16x32_bf16(a[sub][3], bfr[3], acc[sub][t], 0, 0, 0);
        }
    }

    // epilogue 1: BN + relu -> zmid (bf16, C/D layout -> LDS)
    #pragma unroll
    for (int sub = 0; sub < 2; ++sub)
        #pragma unroll
        for (int t = 0; t < 8; ++t) {
            int col = t * 16 + m;
            float sc = scale_s[col], sh = shift_s[col];
            #pragma unroll
            for (int rr = 0; rr < 4; ++rr) {
                float v = fmaxf(acc[sub][t][rr] * sc + sh, 0.f);
                int row = wv * 32 + sub * 16 + q * 4 + rr;
                zmid[row * 136 + col] = f2bf(v);
            }
        }

    __syncthreads();   // zmid complete

    // A2 frags from zmid
    bf16x8 a2[2][4];
    #pragma unroll
    for (int sub = 0; sub < 2; ++sub) {
        const unsigned short* zr = &zmid[(wv * 32 + sub * 16 + m) * 136];
        #pragma unroll
        for (int k = 0; k < 4; ++k)
            a2[sub][k] = __builtin_bit_cast(bf16x8, *(const uint4*)&zr[k * 32 + q * 8]);
    }

    #pragma unroll
    for (int s2 = 0; s2 < 2; ++s2)
        #pragma unroll
        for (int t = 0; t < 8; ++t)
            acc[s2][t] = (f32x4){0.f, 0.f, 0.f, 0.f};

    // GEMM 2: B-frags from global W2t
    #pragma unroll
    for (int t = 0; t < 8; ++t) {
        const unsigned short* wrow = W2t + (size_t)(t * 16 + m) * D;
        bf16x8 bfr[4];
        #pragma unroll
        for (int k = 0; k < 4; ++k)
            bfr[k] = __builtin_bit_cast(bf16x8, *(const uint4*)&wrow[k * 32 + q * 8]);
        #pragma unroll
        for (int sub = 0; sub < 2; ++sub) {
            acc[sub][t] = __builtin_amdgcn_mfma_f32_16x16x32_bf16(a2[sub][0], bfr[0], acc[sub][t], 0, 0, 0);
            acc[sub][t] = __builtin_amdgcn_mfma_f32_16x16x32_bf16(a2[sub][1], bfr[1], acc[sub][t], 0, 0, 0);
            acc[sub][t] = __builtin_amdgcn_mfma_f32_16x16x32_bf16(a2[sub][2], bfr[2], acc[sub][t], 0, 0, 0);
            acc[sub][t] = __builtin_amdgcn_mfma_f32_16x16x32_bf16(a2[sub][3], bfr[3], acc[sub][t], 0, 0, 0);
        }
    }

    // epilogue 2: bias + relu -> hout (bf16). No atomics.
    #pragma unroll
    for (int sub = 0; sub < 2; ++sub)
        #pragma unroll
        for (int rr = 0; rr < 4; ++rr) {
            int node = node0 + wv * 32 + sub * 16 + q * 4 + rr;
            if (node < N_NODES) {
                unsigned short* hrow = hout_b + (size_t)node * D;
                #pragma unroll
                for (int t = 0; t < 8; ++t) {
                    int col = t * 16 + m;
                    hrow[col] = f2bf(fmaxf(acc[sub][t][rr] + b2_s[col], 0.f));
                }
            }
        }
}

// ---------------------------------------------------------------------------
// Pool: segmented sum over sorted batch (bf16 in, fp32 out). 512 threads,
// 4-way row split + LDS combine. No atomics.
// ---------------------------------------------------------------------------
__global__ __launch_bounds__(512) void pool_kernel(
    const unsigned short* __restrict__ hout_b, const int* __restrict__ goff,
    float* __restrict__ pool, int layer_off)
{
    __shared__ float part[3][128];
    const int g = blockIdx.x;
    const int j = threadIdx.x & 127;
    const int grp = threadIdx.x >> 7;         // 0..3
    const int beg = goff[g], end = goff[g + 1];
    const int len = end - beg;
    const int ch  = (len + 3) >> 2;
    int lo = beg + grp * ch;
    int hi = lo + ch;
    if (hi > end) hi = end;
    float acc = 0.0f;
    for (int r = lo; r < hi; ++r)
        acc += bf2f(hout_b[(size_t)r * D + j]);
    if (grp) part[grp - 1][j] = acc;
    __syncthreads();
    if (grp == 0)
        pool[g * (LAYERS * D) + layer_off + j] =
            acc + part[0][j] + part[1][j] + part[2][j];
}

// ---------------------------------------------------------------------------
// Head: out[g] = relu(pool[g] @ lin1_W + lin1_b) @ lin2_W + lin2_b
// ---------------------------------------------------------------------------
__global__ __launch_bounds__(384) void head_kernel(
    const float* __restrict__ pool,
    const float* __restrict__ lin1W,
    const float* __restrict__ lin1b,
    const float* __restrict__ lin2W,
    const float* __restrict__ lin2b,
    float*       __restrict__ out)
{
    __shared__ float gs[LAYERS * D];
    __shared__ float red[LAYERS * D];
    const int g   = blockIdx.x;
    const int tid = threadIdx.x;
    gs[tid] = pool[g * (LAYERS * D) + tid];
    __syncthreads();

    float acc = lin1b[tid];
    #pragma unroll 4
    for (int k = 0; k < LAYERS * D; ++k)
        acc = fmaf(gs[k], lin1W[k * (LAYERS * D) + tid], acc);
    acc = fmaxf(acc, 0.0f);
    float p = acc * lin2W[tid];

    red[tid] = p;
    __syncthreads();
    if (tid < 128) red[tid] = red[tid] + red[tid + 128] + red[tid + 256];
    __syncthreads();
    if (tid < 64) {
        float v = red[tid] + red[tid + 64];
        v += __shfl_down(v, 32);
        v += __shfl_down(v, 16);
        v += __shfl_down(v, 8);
        v += __shfl_down(v, 4);
        v += __shfl_down(v, 2);
        v += __shfl_down(v, 1);
        if (tid == 0) out[g] = v + lin2b[0];
    }
}

// ---------------------------------------------------------------------------
extern "C" void kernel_launch(void* const* d_in, const int* in_sizes, int n_in,
                              void* d_out, int out_size, void* d_ws, size_t ws_size,
                              hipStream_t stream)
{
    const float* x         = (const float*)d_in[0];
    const float* edge_attr = (const float*)d_in[1];
    const float* elW       = (const float*)d_in[2];
    const float* elb       = (const float*)d_in[3];
    const float* W1        = (const float*)d_in[4];
    const float* b1        = (const float*)d_in[5];
    const float* bn_g      = (const float*)d_in[6];
    const float* bn_b      = (const float*)d_in[7];
    const float* bn_mean   = (const float*)d_in[8];
    const float* bn_var    = (const float*)d_in[9];
    const float* W2        = (const float*)d_in[10];
    const float* b2        = (const float*)d_in[11];
    const float* lin1W     = (const float*)d_in[12];
    const float* lin1b     = (const float*)d_in[13];
    const float* lin2W     = (const float*)d_in[14];
    const float* lin2b     = (const float*)d_in[15];
    const int*   ei        = (const int*)d_in[16];
    const int*   batch     = (const int*)d_in[17];
    const int*   src = ei;
    const int*   dst = ei + N_EDGES;

    // Workspace layout, all 16B-aligned:
    float*          pool       = (float*)d_ws;                              // G*384 f32
    unsigned short* xb         = (unsigned short*)(pool + (size_t)N_GRAPHS * LAYERS * D);
    unsigned short* hA_b       = xb   + (size_t)N_NODES * D;                // bf16
    unsigned short* zin_b      = hA_b + (size_t)N_NODES * D;                // bf16
    unsigned short* Wt         = zin_b + (size_t)N_NODES * D;               // 6*16384 bf16
    unsigned*       sorted_eah = (unsigned*)(Wt + 6 * D * D);               // E*8 u32
    int*            sorted_src = (int*)(sorted_eah + (size_t)N_EDGES * 8);
    int*            counts     = sorted_src + N_EDGES;
    int*            offsets    = counts + N_NODES;
    int*            cursor     = offsets + N_NODES + 4;
    int*            goff       = cursor + N_NODES + 4;                      // 513 ints

    hipMemsetAsync(counts, 0, (size_t)N_NODES * sizeof(int), stream);

    // --- once-per-call prep ---
    wprep_kernel<<<6, 256, 0, stream>>>(W1, W2, Wt);
    xprep_kernel<<<(N_NODES * D) / 256, 256, 0, stream>>>(x, xb);
    goff_kernel<<<1, 512, 0, stream>>>(batch, goff);
    hist_kernel<<<N_EDGES / 256, 256, 0, stream>>>(dst, counts);
    scan_kernel<<<1, 1024, 0, stream>>>(counts, offsets, cursor);
    scatter_kernel<<<N_EDGES / 256, 256, 0, stream>>>(
        src, dst, edge_attr, cursor, sorted_src, (uint4*)sorted_eah);

    const unsigned short* hin_b = xb;
    for (int l = 0; l < LAYERS; ++l) {
        aggr_kernel<<<N_NODES, 128, 0, stream>>>(
            hin_b, (const uint4*)sorted_eah, sorted_src, offsets,
            elW + (size_t)l * EF * D, elb + l * D, (unsigned*)zin_b);
        node_mlp<<<(N_NODES + 63) / 64, 128, 0, stream>>>(
            zin_b,
            Wt + (size_t)(l * 2)     * D * D, b1 + l * D,
            bn_g + l * D, bn_b + l * D, bn_mean + l * D, bn_var + l * D,
            Wt + (size_t)(l * 2 + 1) * D * D, b2 + l * D,
            hA_b);
        pool_kernel<<<N_GRAPHS, 512, 0, stream>>>(hA_b, goff, pool, l * D);
        hin_b = hA_b;
    }

    head_kernel<<<N_GRAPHS, LAYERS * D, 0, stream>>>(
        pool, lin1W, lin1b, lin2W, lin2b, (float*)d_out);
}